// Round 6
// baseline (4124.714 us; speedup 1.0000x reference)
//
#include <hip/hip_runtime.h>

#define BATCH 65536
#define DIN   256
#define DHID  512
#define BM    32
#define APAD  264   // 256+8 shorts -> 132-word row stride; stride mod 32 = 4 -> 2-way (free)
#define HPADW 520   // 512+8 shorts -> 260-word row stride; mod 32 = 4 -> 2-way (free)
#define NSTEPS 4

typedef __attribute__((ext_vector_type(8))) short short8;
typedef __attribute__((ext_vector_type(4))) float f32x4;

__device__ __forceinline__ unsigned short f2bf(float f){
  union { float f; unsigned u; } v; v.f = f;
  unsigned u = v.u;
  unsigned r = (u + 0x7FFFu + ((u >> 16) & 1u)) >> 16;   // RN-even
  return (unsigned short)r;
}
__device__ __forceinline__ float bf2f(unsigned short h){
  union { float f; unsigned u; } v; v.u = ((unsigned)h) << 16; return v.f;
}
__device__ __forceinline__ float tanh_fast(float x){
  float e = __expf(2.0f * x);
  return 1.0f - 2.0f / (e + 1.0f);
}

// W1[256][512] -> W1T hi/lo [512][256]; W2[512][256] -> W2T hi/lo [256][512].
__global__ void prep_weights(const float* __restrict__ W1, const float* __restrict__ W2,
                             unsigned short* __restrict__ W1h, unsigned short* __restrict__ W1l,
                             unsigned short* __restrict__ W2h, unsigned short* __restrict__ W2l){
  int idx = blockIdx.x * blockDim.x + threadIdx.x;
  if (idx >= DIN * DHID) return;
  {
    int k = idx / DHID, n = idx % DHID;
    float v = W1[idx];
    unsigned short h = f2bf(v);
    W1h[n * DIN + k] = h;
    W1l[n * DIN + k] = f2bf(v - bf2f(h));
  }
  {
    int k = idx / DIN, n = idx % DIN;
    float v = W2[idx];
    unsigned short h = f2bf(v);
    W2h[n * DHID + k] = h;
    W2l[n * DHID + k] = f2bf(v - bf2f(h));
  }
}

// Persistent RK4 integrator, restructured for latency hiding (round-5 was
// 9 barrier-separated micro-phases/eval at 10% MfmaUtil):
//  - GEMM1 is full-width: each wave owns 32 rows x 64 U-cols (8 independent
//    MFMA chains), all 512 hidden cols in one pass -> no chunk loop.
//  - 2 barriers per eval: [A-write | bar | GEMM1, tanh+H-write | bar |
//    GEMM2, RK]. Safety: A-write (next eval) happens after the post-H bar,
//    by which point every wave has finished its GEMM1 Ash reads; GEMM2
//    reads Hsh written before that same bar; next eval's H-write happens
//    after the next A-bar, by which point all GEMM2 Hsh reads are done.
//  - Register peak ~110 (GEMM1: y16+A16+acc1 32 + frags) -> 128-VGPR tier,
//    no spill (rounds 2-4 lesson: exceed the allocator's tier -> GBs of
//    scratch traffic).
__global__ __launch_bounds__(512, 1)
void ode_all(const float* __restrict__ x, float* __restrict__ out,
             const unsigned short* __restrict__ W1h, const unsigned short* __restrict__ W1l,
             const unsigned short* __restrict__ W2h, const unsigned short* __restrict__ W2l,
             const float* __restrict__ b1, const float* __restrict__ b2)
{
  __shared__ unsigned short Ash[BM * APAD];    // 16.9 KB
  __shared__ unsigned short Hsh[BM * HPADW];   // 33.3 KB  (total 49 KB -> 2 blocks/CU)

  const int tid  = threadIdx.x;
  const int lane = tid & 63;
  const int wid  = tid >> 6;     // 0..7
  const int l15  = lane & 15;
  const int l4   = lane >> 4;    // 0..3
  const size_t r0 = (size_t)blockIdx.x * BM;

  // biases in registers
  float b1v[4];
  #pragma unroll
  for (int nt = 0; nt < 4; ++nt) b1v[nt] = b1[wid * 64 + nt * 16 + l15];
  float b2v[2];
  #pragma unroll
  for (int nt = 0; nt < 2; ++nt) b2v[nt] = b2[wid * 32 + nt * 16 + l15];

  // y/A/F in MFMA C-layout: row = rt*16 + l4*4 + r, col = wid*32 + nt*16 + l15
  float y[2][2][4], A[2][2][4];
  f32x4 F[2][2];
  #pragma unroll
  for (int rt = 0; rt < 2; ++rt)
    #pragma unroll
    for (int nt = 0; nt < 2; ++nt)
      #pragma unroll
      for (int r = 0; r < 4; ++r)
        y[rt][nt][r] = x[(r0 + rt * 16 + l4 * 4 + r) * DIN + wid * 32 + nt * 16 + l15];

  const float h = 1.0f / (float)NSTEPS;

  #pragma unroll 1
  for (int s = 0; s < NSTEPS; ++s){
    #pragma unroll 1
    for (int st = 0; st < 4; ++st){
      // ---- stage input X -> Ash (bf16). st0: y; st1/2: y+(h/2)k; st3: y+h*k ----
      const float cX = (st == 3) ? h : 0.5f * h;
      #pragma unroll
      for (int rt = 0; rt < 2; ++rt)
        #pragma unroll
        for (int nt = 0; nt < 2; ++nt)
          #pragma unroll
          for (int r = 0; r < 4; ++r){
            float xv = (st == 0) ? y[rt][nt][r]
                                 : fmaf(cX, F[rt][nt][r] + b2v[nt], y[rt][nt][r]);
            Ash[(rt * 16 + l4 * 4 + r) * APAD + wid * 32 + nt * 16 + l15] = f2bf(xv);
          }
      __syncthreads();                                   // BAR1: Ash ready

      // ---- GEMM1 full-width: U[32][wid*64 .. +64] = X * W1 (2-term W split) ----
      f32x4 acc1[2][4];
      #pragma unroll
      for (int rt = 0; rt < 2; ++rt)
        #pragma unroll
        for (int nt = 0; nt < 4; ++nt)
          acc1[rt][nt] = (f32x4){0.f, 0.f, 0.f, 0.f};

      #pragma unroll
      for (int ks = 0; ks < 8; ++ks){
        short8 af0 = *reinterpret_cast<const short8*>(&Ash[(     l15) * APAD + ks * 32 + l4 * 8]);
        short8 af1 = *reinterpret_cast<const short8*>(&Ash[(16 + l15) * APAD + ks * 32 + l4 * 8]);
        #pragma unroll
        for (int nt = 0; nt < 4; ++nt){
          int ncol = wid * 64 + nt * 16 + l15;
          int boff = ncol * DIN + ks * 32 + l4 * 8;
          short8 bh = *reinterpret_cast<const short8*>(W1h + boff);
          short8 bl = *reinterpret_cast<const short8*>(W1l + boff);
          acc1[0][nt] = __builtin_amdgcn_mfma_f32_16x16x32_bf16(af0, bh, acc1[0][nt], 0, 0, 0);
          acc1[0][nt] = __builtin_amdgcn_mfma_f32_16x16x32_bf16(af0, bl, acc1[0][nt], 0, 0, 0);
          acc1[1][nt] = __builtin_amdgcn_mfma_f32_16x16x32_bf16(af1, bh, acc1[1][nt], 0, 0, 0);
          acc1[1][nt] = __builtin_amdgcn_mfma_f32_16x16x32_bf16(af1, bl, acc1[1][nt], 0, 0, 0);
        }
      }

      // ---- bias + tanh -> Hsh (wave's 64 cols of all 512) ----
      #pragma unroll
      for (int nt = 0; nt < 4; ++nt)
        #pragma unroll
        for (int rt = 0; rt < 2; ++rt)
          #pragma unroll
          for (int r = 0; r < 4; ++r){
            float t = tanh_fast(acc1[rt][nt][r] + b1v[nt]);
            Hsh[(rt * 16 + l4 * 4 + r) * HPADW + wid * 64 + nt * 16 + l15] = f2bf(t);
          }
      __syncthreads();                                   // BAR2: Hsh ready, Ash free

      // ---- GEMM2: F[32][wid*32 .. +32] = H * W2 (2-term W split), K = 512 ----
      #pragma unroll
      for (int rt = 0; rt < 2; ++rt)
        #pragma unroll
        for (int nt = 0; nt < 2; ++nt)
          F[rt][nt] = (f32x4){0.f, 0.f, 0.f, 0.f};

      #pragma unroll
      for (int ks = 0; ks < 16; ++ks){
        short8 hf0 = *reinterpret_cast<const short8*>(&Hsh[(     l15) * HPADW + ks * 32 + l4 * 8]);
        short8 hf1 = *reinterpret_cast<const short8*>(&Hsh[(16 + l15) * HPADW + ks * 32 + l4 * 8]);
        #pragma unroll
        for (int nt = 0; nt < 2; ++nt){
          int ncol = wid * 32 + nt * 16 + l15;
          int boff = ncol * DHID + ks * 32 + l4 * 8;
          short8 bh = *reinterpret_cast<const short8*>(W2h + boff);
          short8 bl = *reinterpret_cast<const short8*>(W2l + boff);
          F[0][nt] = __builtin_amdgcn_mfma_f32_16x16x32_bf16(hf0, bh, F[0][nt], 0, 0, 0);
          F[0][nt] = __builtin_amdgcn_mfma_f32_16x16x32_bf16(hf0, bl, F[0][nt], 0, 0, 0);
          F[1][nt] = __builtin_amdgcn_mfma_f32_16x16x32_bf16(hf1, bh, F[1][nt], 0, 0, 0);
          F[1][nt] = __builtin_amdgcn_mfma_f32_16x16x32_bf16(hf1, bl, F[1][nt], 0, 0, 0);
        }
      }

      // ---- RK4 state update (k_st = F + b2) ----
      if (st == 0){
        #pragma unroll
        for (int rt = 0; rt < 2; ++rt)
          #pragma unroll
          for (int nt = 0; nt < 2; ++nt)
            #pragma unroll
            for (int r = 0; r < 4; ++r)
              A[rt][nt][r] = fmaf(h / 6.0f, F[rt][nt][r] + b2v[nt], y[rt][nt][r]);
      } else if (st == 1 || st == 2){
        #pragma unroll
        for (int rt = 0; rt < 2; ++rt)
          #pragma unroll
          for (int nt = 0; nt < 2; ++nt)
            #pragma unroll
            for (int r = 0; r < 4; ++r)
              A[rt][nt][r] = fmaf(h / 3.0f, F[rt][nt][r] + b2v[nt], A[rt][nt][r]);
      } else {
        #pragma unroll
        for (int rt = 0; rt < 2; ++rt)
          #pragma unroll
          for (int nt = 0; nt < 2; ++nt)
            #pragma unroll
            for (int r = 0; r < 4; ++r)
              y[rt][nt][r] = fmaf(h / 6.0f, F[rt][nt][r] + b2v[nt], A[rt][nt][r]);
      }
    }
  }

  // ---- write final state ----
  #pragma unroll
  for (int rt = 0; rt < 2; ++rt)
    #pragma unroll
    for (int nt = 0; nt < 2; ++nt)
      #pragma unroll
      for (int r = 0; r < 4; ++r)
        out[(r0 + rt * 16 + l4 * 4 + r) * DIN + wid * 32 + nt * 16 + l15] = y[rt][nt][r];
}

extern "C" void kernel_launch(void* const* d_in, const int* in_sizes, int n_in,
                              void* d_out, int out_size, void* d_ws, size_t ws_size,
                              hipStream_t stream)
{
  const float* x  = (const float*)d_in[0];
  const float* W1 = (const float*)d_in[1];
  const float* b1 = (const float*)d_in[2];
  const float* W2 = (const float*)d_in[3];
  const float* b2 = (const float*)d_in[4];
  float* out = (float*)d_out;

  unsigned short* W1h = (unsigned short*)d_ws;
  unsigned short* W1l = W1h + DIN * DHID;
  unsigned short* W2h = W1l + DIN * DHID;
  unsigned short* W2l = W2h + DIN * DHID;   // 1 MiB total

  prep_weights<<<512, 256, 0, stream>>>(W1, W2, W1h, W1l, W2h, W2l);
  ode_all<<<BATCH / BM, 512, 0, stream>>>(x, out, W1h, W1l, W2h, W2l, b1, b2);
}